// Round 1
// baseline (309.548 us; speedup 1.0000x reference)
//
#include <hip/hip_runtime.h>
#include <hip/hip_fp8.h>
#include <cstdint>
#include <cmath>

// Problem constants
#define B_   4
#define C_   512
#define HW_  4096
#define G_   32
#define CPG_ 16
#define EPS_ 1e-6f
#define SCALE_ 0.04419417382415922f  // 1/sqrt(512)
#define PSCALE_ 0.0625f              // P pre-scale; cancels in acc/rowsum ratio

// ---------------------------------------------------------------------------
// Column permutation (sigma): GEMM epilogues store outputs in the MFMA
// C-layout packed order. Within each 64-col group, stored position
// p = fr*4 + j holds true column c = j*16 + fr. Invariant under contraction
// as long as producer & consumer agree.
//
// Weight scaling: fp8 weights are stored x16; the MFMA e8m0 scale operand
// 0x7B (= 2^-4) folds the 1/16 back in HW. Same trick for hmT8.
//
// R9 change: sexp_gemm + pv_gemm fused into fused_attn_kernel (flash-style).
// P8 (64 MB) no longer materialized. Q register-resident, K double-buffered
// LDS with counted-vmcnt raw barriers, V direct L2->reg, P through an 8 KB
// LDS transpose buffer, rowsum via ones-MFMA.
// ---------------------------------------------------------------------------

typedef __bf16 bf16_t;
typedef __bf16 bf16x8 __attribute__((ext_vector_type(8)));
typedef float  f32x4  __attribute__((ext_vector_type(4)));
typedef int    i32x4  __attribute__((ext_vector_type(4)));
typedef int    i32x8  __attribute__((ext_vector_type(8)));
typedef unsigned int u32;
typedef __hip_fp8_e4m3 fp8_t;  // OCP e4m3fn on gfx950

// Async global->LDS copy, 16B per lane. LDS dest is wave-uniform base + lane*16.
__device__ __forceinline__ void cp16(const void* g, void* l) {
  __builtin_amdgcn_global_load_lds((__attribute__((address_space(1))) u32*)(g),
                                   (__attribute__((address_space(3))) u32*)(l),
                                   16, 0, 0);
}

__device__ __forceinline__ void zero_acc(f32x4 acc[4][4]) {
  f32x4 z = {0.f, 0.f, 0.f, 0.f};
#pragma unroll
  for (int i = 0; i < 4; ++i)
#pragma unroll
    for (int j = 0; j < 4; ++j) acc[i][j] = z;
}

// MX-fp8 BT GEMM mainloop (BK=128): mfma_scale_f32_16x16x128_f8f6f4, fmt 0
// (e4m3), per-operand e8m0 scales SA/SB (0x7F = 1.0, 0x7B = 2^-4).
// Used by the small square GEMMs (qkv / v / proj).
template <bool ROWSUM, int SA = 0x7F, int SB = 0x7F>
__device__ __forceinline__ void gemm_bt_mx(const unsigned char* __restrict__ A,
                                           const unsigned char* __restrict__ B,
                                           int K, int lda, int ldb,
                                           f32x4 acc[4][4], f32x4 accl[4]) {
  __shared__ __align__(16) unsigned char As[128 * 128];
  __shared__ __align__(16) unsigned char Bs[128 * 128];
  const int tid  = threadIdx.x;
  const int wave = tid >> 6;
  const int lane = tid & 63;
  const int wm = (wave >> 1) * 64;
  const int wn = (wave & 1) * 64;
  const int srow = lane >> 3;
  const int gch  = ((lane & 7) - srow) & 7;
  const unsigned char* gA = A + (size_t)(wave * 32 + srow) * lda + gch * 16;
  const unsigned char* gB = B + (size_t)(wave * 32 + srow) * ldb + gch * 16;
  unsigned char* lA = As + wave * 32 * 128;
  unsigned char* lB = Bs + wave * 32 * 128;
  const int fr = lane & 15;
  const int q  = lane >> 4;
  const int co0 = ((2 * q     + fr) & 7) * 16;
  const int co1 = ((2 * q + 1 + fr) & 7) * 16;
  const i32x8 vones = {0x38383838, 0x38383838, 0x38383838, 0x38383838,
                       0x38383838, 0x38383838, 0x38383838, 0x38383838};

  for (int k0 = 0; k0 < K; k0 += 128) {
#pragma unroll
    for (int cc = 0; cc < 4; ++cc) {
      cp16(gA + (size_t)(cc * 8) * lda, lA + cc * 1024);
      cp16(gB + (size_t)(cc * 8) * ldb, lB + cc * 1024);
    }
    gA += 128; gB += 128;
    __syncthreads();
    i32x8 a[4], b[4];
#pragma unroll
    for (int i = 0; i < 4; ++i) {
      const int ro = (wm + i * 16 + fr) * 128;
      i32x4 lo = *(const i32x4*)(As + ro + co0);
      i32x4 hi = *(const i32x4*)(As + ro + co1);
      a[i] = __builtin_shufflevector(lo, hi, 0, 1, 2, 3, 4, 5, 6, 7);
    }
#pragma unroll
    for (int j = 0; j < 4; ++j) {
      const int ro = (wn + j * 16 + fr) * 128;
      i32x4 lo = *(const i32x4*)(Bs + ro + co0);
      i32x4 hi = *(const i32x4*)(Bs + ro + co1);
      b[j] = __builtin_shufflevector(lo, hi, 0, 1, 2, 3, 4, 5, 6, 7);
    }
#pragma unroll
    for (int i = 0; i < 4; ++i) {
#pragma unroll
      for (int j = 0; j < 4; ++j)
        acc[i][j] = __builtin_amdgcn_mfma_scale_f32_16x16x128_f8f6f4(
            a[i], b[j], acc[i][j], 0, 0, 0, SA, 0, SB);
      if (ROWSUM)
        accl[i] = __builtin_amdgcn_mfma_scale_f32_16x16x128_f8f6f4(
            a[i], vones, accl[i], 0, 0, 0, SA, 0, 0x7F);
    }
    __syncthreads();
  }
}

// ---------------- small prep kernels ----------------

__global__ void __launch_bounds__(256) cast_w_kernel(const float* __restrict__ qkv_w,
                                                     const float* __restrict__ proj_w,
                                                     fp8_t* __restrict__ wqkv8,
                                                     fp8_t* __restrict__ wproj8) {
  const int idx = blockIdx.x * 256 + threadIdx.x;   // quad index
  const int t = idx * 4;
  const int nq = 1536 * 512;
  if (t < nq) {
    u32 dw = 0;
    dw = (u32)__builtin_amdgcn_cvt_pk_fp8_f32(qkv_w[t] * 16.f, qkv_w[t + 1] * 16.f, (int)dw, false);
    dw = (u32)__builtin_amdgcn_cvt_pk_fp8_f32(qkv_w[t + 2] * 16.f, qkv_w[t + 3] * 16.f, (int)dw, true);
    *(u32*)((unsigned char*)wqkv8 + t) = dw;
  } else {
    const int tt = t - nq;          // o*512 + p, p multiple of 4
    const int o = tt >> 9;
    const int p = tt & 511;
    float v[4];
#pragma unroll
    for (int e = 0; e < 4; ++e) {
      const int pe = p + e;
      const int off = pe & 63;
      const int c = (pe & ~63) + ((off & 3) << 4) + (off >> 2);  // sigma(pe)
      v[e] = proj_w[(o << 9) + c] * 16.f;
    }
    u32 dw = 0;
    dw = (u32)__builtin_amdgcn_cvt_pk_fp8_f32(v[0], v[1], (int)dw, false);
    dw = (u32)__builtin_amdgcn_cvt_pk_fp8_f32(v[2], v[3], (int)dw, true);
    *(u32*)((unsigned char*)wproj8 + tt) = dw;
  }
}

__global__ void __launch_bounds__(256) gn_partial_kernel(const float* __restrict__ x,
                                                         float* __restrict__ stats) {
  __shared__ float rs[256], rss[256];
  const int bg = blockIdx.x >> 3;       // group id 0..127
  const int ch = blockIdx.x & 7;        // hw chunk 0..7
  const float4* base = (const float4*)(x + (size_t)bg * (CPG_ * HW_)) +
                       (size_t)ch * (CPG_ * HW_ / 4 / 8);
  float s = 0.f, ss = 0.f;
  for (int i = threadIdx.x; i < CPG_ * HW_ / 4 / 8; i += 256) {
    float4 v = base[i];
    s  += v.x + v.y + v.z + v.w;
    ss += v.x * v.x + v.y * v.y + v.z * v.z + v.w * v.w;
  }
  rs[threadIdx.x] = s; rss[threadIdx.x] = ss;
  __syncthreads();
  for (int st = 128; st > 0; st >>= 1) {
    if ((int)threadIdx.x < st) {
      rs[threadIdx.x]  += rs[threadIdx.x + st];
      rss[threadIdx.x] += rss[threadIdx.x + st];
    }
    __syncthreads();
  }
  if (threadIdx.x == 0) {
    atomicAdd(&stats[bg * 2 + 0], rs[0]);
    atomicAdd(&stats[bg * 2 + 1], rss[0]);
  }
}

__global__ void __launch_bounds__(256) norm_tr_kernel(const float* __restrict__ x,
                                                      const float* __restrict__ stats,
                                                      const float* __restrict__ nw,
                                                      const float* __restrict__ nb,
                                                      fp8_t* __restrict__ xnT8) {
  __shared__ float tile[64][65];   // [c_off][i_off]
  const int b  = blockIdx.z;
  const int i0 = blockIdx.x * 64;   // hw
  const int c0 = blockIdx.y * 64;   // channel
  const int tx = threadIdx.x & 63;
  const int ty = threadIdx.x >> 6;  // 0..3
  const int cbase = c0 + ty * 16;
  const int g = cbase >> 4;
  const float inv = 1.f / (float)(CPG_ * HW_);
  const float sum  = stats[(b * G_ + g) * 2 + 0];
  const float ssum = stats[(b * G_ + g) * 2 + 1];
  const float mean = sum * inv;
  const float rstd = rsqrtf(ssum * inv - mean * mean + EPS_);
#pragma unroll
  for (int r = 0; r < 16; ++r) {
    const int c = cbase + r;
    float v = x[((size_t)b * C_ + c) * HW_ + i0 + tx];
    tile[ty * 16 + r][tx] = (v - mean) * rstd * nw[c] + nb[c];
  }
  __syncthreads();
  const int il = threadIdx.x >> 2;
  const int q4 = threadIdx.x & 3;
#pragma unroll
  for (int m = 0; m < 4; ++m) {
    const int cq = q4 + m * 4;     // 0..15
    u32 dw = 0;
    dw = (u32)__builtin_amdgcn_cvt_pk_fp8_f32(tile[cq * 4 + 0][il], tile[cq * 4 + 1][il], (int)dw, false);
    dw = (u32)__builtin_amdgcn_cvt_pk_fp8_f32(tile[cq * 4 + 2][il], tile[cq * 4 + 3][il], (int)dw, true);
    *(u32*)((unsigned char*)xnT8 + ((size_t)b * HW_ + i0 + il) * C_ + c0 + cq * 4) = dw;
  }
}

// ---------------- GEMM kernels ----------------

__global__ void __launch_bounds__(256) qk_gemm_kernel(const fp8_t* __restrict__ xnT8,
                                                      const fp8_t* __restrict__ wqkv8,
                                                      const float* __restrict__ qkv_b,
                                                      fp8_t* __restrict__ QKt8) {
  const int b = blockIdx.z;
  f32x4 acc[4][4]; zero_acc(acc);
  const unsigned char* A  = (const unsigned char*)xnT8 + ((size_t)b * HW_ + blockIdx.y * 128) * C_;
  const unsigned char* Bp = (const unsigned char*)wqkv8 + (size_t)blockIdx.x * 128 * C_;
  gemm_bt_mx<false, 0x7F, 0x7B>(A, Bp, C_, C_, C_, acc, nullptr);
  const int lane = threadIdx.x & 63, wave = threadIdx.x >> 6;
  const int wm = (wave >> 1) * 64, wn = (wave & 1) * 64;
  const int fr = lane & 15, q = lane >> 4;
  const int r0 = blockIdx.y * 128 + wm + (q << 2);
  const int cb = blockIdx.x * 128 + wn;
  float bias[4];
#pragma unroll
  for (int j = 0; j < 4; ++j) bias[j] = qkv_b[cb + fr + j * 16];
#pragma unroll
  for (int i = 0; i < 4; ++i)
#pragma unroll
    for (int r = 0; r < 4; ++r) {
      const int row = r0 + i * 16 + r;
      u32 dw = 0;
      dw = (u32)__builtin_amdgcn_cvt_pk_fp8_f32(acc[i][0][r] + bias[0],
                                                acc[i][1][r] + bias[1], (int)dw, false);
      dw = (u32)__builtin_amdgcn_cvt_pk_fp8_f32(acc[i][2][r] + bias[2],
                                                acc[i][3][r] + bias[3], (int)dw, true);
      *(u32*)((unsigned char*)QKt8 + ((size_t)b * HW_ + row) * 1024 + cb + fr * 4) = dw;
    }
}

__global__ void __launch_bounds__(256) v_gemm_kernel(const fp8_t* __restrict__ wqkv8,
                                                     const fp8_t* __restrict__ xnT8,
                                                     const float* __restrict__ qkv_b,
                                                     fp8_t* __restrict__ V8) {
  const int b = blockIdx.z;
  f32x4 acc[4][4]; zero_acc(acc);
  const unsigned char* A  = (const unsigned char*)wqkv8 + (size_t)(1024 + blockIdx.y * 128) * C_;
  const unsigned char* Bp = (const unsigned char*)xnT8 + ((size_t)b * HW_ + blockIdx.x * 128) * C_;
  gemm_bt_mx<false, 0x7B, 0x7F>(A, Bp, C_, C_, C_, acc, nullptr);
  const int lane = threadIdx.x & 63, wave = threadIdx.x >> 6;
  const int wm = (wave >> 1) * 64, wn = (wave & 1) * 64;
  const int fr = lane & 15, q = lane >> 4;
  const int r0 = blockIdx.y * 128 + wm + (q << 2);
  const int cb = blockIdx.x * 128 + wn;
#pragma unroll
  for (int i = 0; i < 4; ++i)
#pragma unroll
    for (int r = 0; r < 4; ++r) {
      const int row = r0 + i * 16 + r;        // c channel (row of V8)
      const float bias = qkv_b[1024 + row];
      u32 dw = 0;
      dw = (u32)__builtin_amdgcn_cvt_pk_fp8_f32(acc[i][0][r] + bias,
                                                acc[i][1][r] + bias, (int)dw, false);
      dw = (u32)__builtin_amdgcn_cvt_pk_fp8_f32(acc[i][2][r] + bias,
                                                acc[i][3][r] + bias, (int)dw, true);
      *(u32*)((unsigned char*)V8 + ((size_t)b * C_ + row) * HW_ + cb + fr * 4) = dw;
    }
}

// ---------------------------------------------------------------------------
// Fused attention: S = exp(scale*QK^T) and H = (S.V)/rowsum(S), flash-style.
// Grid: 256 blocks = 4 batches x 64 Q-panels (64 rows), 512 threads (8 waves).
//   wave w: ih = w&1 -> 32-row half (S rows AND PV rows)
//           jq = w>>1 -> S col quarter (32 of 128)  /  PV channel group (128 of 512)
// Per block:
//   - Q panel (64x512 fp8) staged once, preloaded into regs (qf, 64 VGPR/wave).
//   - loop over 32 j-panels (128 wide): K panel (128x512) double-buffered in
//     LDS (mod-32 chunk rotation), staged with cp16 + raw barriers with
//     COUNTED vmcnt(8) so the next stage stays in flight (T3/T4).
//   - S epilogue: exp -> fp8 -> P (64x128) into 8 KB LDS, sigma-packed with
//     mod-8 chunk rotation (same stored byte order as V8's j columns).
//   - PV: P A-frags from LDS, V B-frags loaded straight from global (L2-hot,
//     XCD-mapped so each batch owns an XCD pair), pipelined 3 frags ahead.
//   - rowsum via ones-MFMA (identical numerics to the old pv_gemm).
// ---------------------------------------------------------------------------
__global__ void __launch_bounds__(512, 2)
fused_attn_kernel(const fp8_t* __restrict__ QKt8, const fp8_t* __restrict__ V8,
                  fp8_t* __restrict__ hmT8) {
  __shared__ __align__(16) unsigned char lds[2 * 65536 + 8192];
  unsigned char* plds = lds + 131072;

  // XCD-aware decode: round-robin heuristic; batch b -> XCDs {2b, 2b+1}
  const int n     = blockIdx.x;
  const int xcd   = n & 7;
  const int b     = xcd >> 1;
  const int panel = (xcd & 1) * 32 + (n >> 3);   // 0..63

  const int tid  = threadIdx.x;
  const int lane = tid & 63;
  const int wave = tid >> 6;
  const int fr   = lane & 15;
  const int q    = lane >> 4;
  const int ih   = wave & 1;
  const int jq   = wave >> 1;   // also PV channel group
  const int cg   = wave >> 1;

  const unsigned char* QKb = (const unsigned char*)QKt8 + (size_t)b * HW_ * 1024;
  const unsigned char* gK  = QKb + 512;   // K half of qkv columns

  const int sch = tid & 31;   // staging chunk within a 512-B row
  const int srw = tid >> 5;   // staging row within a 16-row pass

  // ---- prologue: stage Q (64x512) into kbuf1 region, mod-32 rotation ----
#pragma unroll
  for (int p = 0; p < 4; ++p) {
    const int row = p * 16 + srw;
    cp16(QKb + (size_t)(panel * 64 + row) * 1024 + (((sch - row) & 31) << 4),
         lds + 65536 + row * 512 + sch * 16);
  }
  asm volatile("s_waitcnt vmcnt(0)" ::: "memory");
  __builtin_amdgcn_s_barrier();

  // preload Q fragments: qf[ii][k] covers rows ih*32+ii*16, K-bytes k*128
  i32x8 qf[2][4];
#pragma unroll
  for (int ii = 0; ii < 2; ++ii) {
    const int row = ih * 32 + ii * 16 + fr;
    const unsigned char* qr = lds + 65536 + row * 512;
#pragma unroll
    for (int k = 0; k < 4; ++k) {
      i32x4 lo = *(const i32x4*)(qr + (((k * 8 + 2 * q + row) & 31) << 4));
      i32x4 hi = *(const i32x4*)(qr + (((k * 8 + 2 * q + 1 + row) & 31) << 4));
      qf[ii][k] = __builtin_shufflevector(lo, hi, 0, 1, 2, 3, 4, 5, 6, 7);
    }
  }
  asm volatile("s_waitcnt lgkmcnt(0)" ::: "memory");
  __builtin_amdgcn_s_barrier();   // all waves done reading Q region

  // ---- stage K(0) into kbuf0 ----
#pragma unroll
  for (int p = 0; p < 8; ++p) {
    const int row = p * 16 + srw;
    cp16(gK + (size_t)row * 1024 + (((sch - row) & 31) << 4),
         lds + row * 512 + sch * 16);
  }

  f32x4 pvacc[2][8];
  {
    f32x4 z = {0.f, 0.f, 0.f, 0.f};
#pragma unroll
    for (int i = 0; i < 2; ++i)
#pragma unroll
      for (int j = 0; j < 8; ++j) pvacc[i][j] = z;
  }
  f32x4 accl[2];
  {
    f32x4 z = {0.f, 0.f, 0.f, 0.f};
    accl[0] = z; accl[1] = z;
  }
  const i32x8 vones = {0x38383838, 0x38383838, 0x38383838, 0x38383838,
                       0x38383838, 0x38383838, 0x38383838, 0x38383838};

  const unsigned char* vbase = (const unsigned char*)V8 +
      ((size_t)b * C_ + cg * 128 + fr) * HW_ + q * 32;

  unsigned char* cur = lds;
  unsigned char* nxt = lds + 65536;

  const int kr0 = jq * 32 + fr;
  const int kr1 = kr0 + 16;
  const int offb = (jq >> 1) * 64 + fr * 4 + (jq & 1) * 2;  // P stored byte pos

#pragma unroll 1
  for (int t = 0; t < 32; ++t) {
    // stage next K panel; counted wait keeps it in flight across the barrier
    if (t < 31) {
#pragma unroll
      for (int p = 0; p < 8; ++p) {
        const int row = p * 16 + srw;
        cp16(gK + (size_t)((t + 1) * 128 + row) * 1024 + (((sch - row) & 31) << 4),
             nxt + row * 512 + sch * 16);
      }
      asm volatile("s_waitcnt vmcnt(8)" ::: "memory");   // K(t) resident, K(t+1) flying
    } else {
      asm volatile("s_waitcnt vmcnt(0)" ::: "memory");
    }
    __builtin_amdgcn_s_barrier();   // all K(t) visible; all PV(t-1) P-reads done

    // ---- S phase: sacc[ii][jj] over 4 K-steps (Q from regs, K from LDS) ----
    f32x4 sacc[2][2];
    {
      f32x4 z = {0.f, 0.f, 0.f, 0.f};
      sacc[0][0] = z; sacc[0][1] = z; sacc[1][0] = z; sacc[1][1] = z;
    }
    const unsigned char* k0p = cur + kr0 * 512;
    const unsigned char* k1p = cur + kr1 * 512;
#pragma unroll
    for (int k = 0; k < 4; ++k) {
      i32x4 l0 = *(const i32x4*)(k0p + (((k * 8 + 2 * q + kr0) & 31) << 4));
      i32x4 h0 = *(const i32x4*)(k0p + (((k * 8 + 2 * q + 1 + kr0) & 31) << 4));
      i32x4 l1 = *(const i32x4*)(k1p + (((k * 8 + 2 * q + kr1) & 31) << 4));
      i32x4 h1 = *(const i32x4*)(k1p + (((k * 8 + 2 * q + 1 + kr1) & 31) << 4));
      i32x8 kf0 = __builtin_shufflevector(l0, h0, 0, 1, 2, 3, 4, 5, 6, 7);
      i32x8 kf1 = __builtin_shufflevector(l1, h1, 0, 1, 2, 3, 4, 5, 6, 7);
#pragma unroll
      for (int ii = 0; ii < 2; ++ii) {
        sacc[ii][0] = __builtin_amdgcn_mfma_scale_f32_16x16x128_f8f6f4(
            qf[ii][k], kf0, sacc[ii][0], 0, 0, 0, 0x7F, 0, 0x7F);
        sacc[ii][1] = __builtin_amdgcn_mfma_scale_f32_16x16x128_f8f6f4(
            qf[ii][k], kf1, sacc[ii][1], 0, 0, 0, 0x7F, 0, 0x7F);
      }
    }

    // ---- exp -> fp8 -> P LDS (b16 stores, sigma-packed, mod-8 rotation) ----
#pragma unroll
    for (int ii = 0; ii < 2; ++ii)
#pragma unroll
      for (int r = 0; r < 4; ++r) {
        const int row = ih * 32 + ii * 16 + q * 4 + r;
        float e0 = __expf(sacc[ii][0][r] * SCALE_) * PSCALE_;
        float e1 = __expf(sacc[ii][1][r] * SCALE_) * PSCALE_;
        u32 dw = (u32)__builtin_amdgcn_cvt_pk_fp8_f32(e0, e1, 0, false);
        *(unsigned short*)(plds + row * 128 + ((((offb >> 4) + row) & 7) << 4) +
                           (offb & 15)) = (unsigned short)dw;
      }

    // early V fragment loads (direct global -> regs; L2-hot)
    const unsigned char* vp = vbase + t * 128;
    i32x4 vl[8], vh[8];
#pragma unroll
    for (int c = 0; c < 3; ++c) {
      vl[c] = *(const i32x4*)(vp + (size_t)(c * 16) * HW_);
      vh[c] = *(const i32x4*)(vp + (size_t)(c * 16) * HW_ + 16);
    }

    asm volatile("s_waitcnt lgkmcnt(0)" ::: "memory");  // own P writes done
    __builtin_amdgcn_s_barrier();                       // P(t) visible to all

    // ---- PV phase: pa from P LDS, V rolling from global ----
    i32x8 pa[2];
#pragma unroll
    for (int ii = 0; ii < 2; ++ii) {
      const int prow = ih * 32 + ii * 16 + fr;
      const unsigned char* pp = plds + prow * 128;
      i32x4 lo = *(const i32x4*)(pp + (((2 * q + prow) & 7) << 4));
      i32x4 hi = *(const i32x4*)(pp + (((2 * q + 1 + prow) & 7) << 4));
      pa[ii] = __builtin_shufflevector(lo, hi, 0, 1, 2, 3, 4, 5, 6, 7);
    }
    __builtin_amdgcn_s_setprio(1);
#pragma unroll
    for (int c = 0; c < 8; ++c) {
      if (c < 5) {
        vl[c + 3] = *(const i32x4*)(vp + (size_t)((c + 3) * 16) * HW_);
        vh[c + 3] = *(const i32x4*)(vp + (size_t)((c + 3) * 16) * HW_ + 16);
      }
      i32x8 v = __builtin_shufflevector(vl[c], vh[c], 0, 1, 2, 3, 4, 5, 6, 7);
      pvacc[0][c] = __builtin_amdgcn_mfma_scale_f32_16x16x128_f8f6f4(
          pa[0], v, pvacc[0][c], 0, 0, 0, 0x7F, 0, 0x7F);
      pvacc[1][c] = __builtin_amdgcn_mfma_scale_f32_16x16x128_f8f6f4(
          pa[1], v, pvacc[1][c], 0, 0, 0, 0x7F, 0, 0x7F);
    }
    accl[0] = __builtin_amdgcn_mfma_scale_f32_16x16x128_f8f6f4(
        pa[0], vones, accl[0], 0, 0, 0, 0x7F, 0, 0x7F);
    accl[1] = __builtin_amdgcn_mfma_scale_f32_16x16x128_f8f6f4(
        pa[1], vones, accl[1], 0, 0, 0, 0x7F, 0, 0x7F);
    __builtin_amdgcn_s_setprio(0);

    unsigned char* tmp = cur; cur = nxt; nxt = tmp;
  }

  // ---- epilogue: hmT8 = fp8(16 * pvacc / rowsum), sigma-packed channels ----
  unsigned char* hb = (unsigned char*)hmT8 + (size_t)b * HW_ * C_;
#pragma unroll
  for (int ii = 0; ii < 2; ++ii)
#pragma unroll
    for (int r = 0; r < 4; ++r) {
      const int row = panel * 64 + ih * 32 + ii * 16 + q * 4 + r;
      const float rl = 16.f / accl[ii][r];
#pragma unroll
      for (int g = 0; g < 2; ++g) {
        u32 dw = 0;
        dw = (u32)__builtin_amdgcn_cvt_pk_fp8_f32(pvacc[ii][g * 4 + 0][r] * rl,
                                                  pvacc[ii][g * 4 + 1][r] * rl, (int)dw, false);
        dw = (u32)__builtin_amdgcn_cvt_pk_fp8_f32(pvacc[ii][g * 4 + 2][r] * rl,
                                                  pvacc[ii][g * 4 + 3][r] * rl, (int)dw, true);
        *(u32*)(hb + (size_t)row * C_ + cg * 128 + g * 64 + fr * 4) = dw;
      }
    }
}

// out[b][o][i] = x[b][o][i] + proj_b[o] + (wproj8*2^-4)(sigma) . (hmT8*2^-4)(sigma)
__global__ void __launch_bounds__(256) proj_gemm_kernel(const fp8_t* __restrict__ wproj8,
                                                        const fp8_t* __restrict__ hmT8,
                                                        const float* __restrict__ proj_b,
                                                        const float* __restrict__ x,
                                                        float* __restrict__ out) {
  const int b = blockIdx.z;
  f32x4 acc[4][4]; zero_acc(acc);
  const unsigned char* A  = (const unsigned char*)wproj8 + (size_t)blockIdx.y * 128 * C_;
  const unsigned char* Bp = (const unsigned char*)hmT8 + ((size_t)b * HW_ + blockIdx.x * 128) * C_;
  gemm_bt_mx<false, 0x7B, 0x7B>(A, Bp, C_, C_, C_, acc, nullptr);
  const int lane = threadIdx.x & 63, wave = threadIdx.x >> 6;
  const int wm = (wave >> 1) * 64, wn = (wave & 1) * 64;
  const int r0 = blockIdx.y * 128 + wm + ((lane >> 4) << 2);
  const int c0 = blockIdx.x * 128 + wn + (lane & 15);
#pragma unroll
  for (int i = 0; i < 4; ++i)
#pragma unroll
    for (int r = 0; r < 4; ++r) {
      const int row = r0 + i * 16 + r;
      const float bias = proj_b[row];
#pragma unroll
      for (int j = 0; j < 4; ++j) {
        const int col = c0 + j * 16;
        const size_t idx = ((size_t)b * C_ + row) * HW_ + col;
        out[idx] = x[idx] + bias + acc[i][j][r];
      }
    }
}

// ---------------- launch ----------------
// Workspace layout (bytes), total ~43 MB (P8 no longer materialized):
//   wqkv8  fp8 [1536][512] (x16)         786,432
//   wproj8 fp8 [512][512] (x16, sigma)   262,144
//   stats  f32 [128][2]                    1,024
//   xnT8   fp8 [4][4096][512]          8,388,608
//   QKt8   fp8 [4][4096][1024](sig)   16,777,216
//   V8     fp8 [4][512][4096] (sig)    8,388,608
//   hmT8   fp8 [4][4096][512] (x16,sig) 8,388,608
extern "C" void kernel_launch(void* const* d_in, const int* in_sizes, int n_in,
                              void* d_out, int out_size, void* d_ws, size_t ws_size,
                              hipStream_t stream) {
  const float* x      = (const float*)d_in[0];
  const float* norm_w = (const float*)d_in[1];
  const float* norm_b = (const float*)d_in[2];
  const float* qkv_w  = (const float*)d_in[3];
  const float* qkv_b  = (const float*)d_in[4];
  const float* proj_w = (const float*)d_in[5];
  const float* proj_b = (const float*)d_in[6];
  float* out = (float*)d_out;

  char* ws = (char*)d_ws;
  size_t o = 0;
  fp8_t* wqkv8  = (fp8_t*)(ws + o); o += (size_t)1536 * 512;
  fp8_t* wproj8 = (fp8_t*)(ws + o); o += (size_t)512 * 512;
  float* stats  = (float*)(ws + o); o += 128 * 2 * 4;
  fp8_t* xnT8   = (fp8_t*)(ws + o); o += (size_t)B_ * HW_ * C_;
  fp8_t* QKt8   = (fp8_t*)(ws + o); o += (size_t)B_ * HW_ * 1024;
  fp8_t* V8     = (fp8_t*)(ws + o); o += (size_t)B_ * C_ * HW_;
  fp8_t* hmT8   = (fp8_t*)(ws + o); o += (size_t)B_ * HW_ * C_;

  cast_w_kernel<<<1024, 256, 0, stream>>>(qkv_w, proj_w, wqkv8, wproj8);
  hipMemsetAsync(stats, 0, 128 * 2 * sizeof(float), stream);
  gn_partial_kernel<<<1024, 256, 0, stream>>>(x, stats);
  norm_tr_kernel<<<dim3(HW_ / 64, C_ / 64, B_), 256, 0, stream>>>(x, stats, norm_w, norm_b, xnT8);
  qk_gemm_kernel<<<dim3(1024 / 128, HW_ / 128, B_), 256, 0, stream>>>(xnT8, wqkv8, qkv_b, QKt8);
  v_gemm_kernel<<<dim3(HW_ / 128, C_ / 128, B_), 256, 0, stream>>>(wqkv8, xnT8, qkv_b, V8);
  fused_attn_kernel<<<256, 512, 0, stream>>>(QKt8, V8, hmT8);
  proj_gemm_kernel<<<dim3(HW_ / 128, C_ / 128, B_), 256, 0, stream>>>(
      wproj8, hmT8, proj_b, x, out);
}